// Round 12
// baseline (197.049 us; speedup 1.0000x reference)
//
#include <hip/hip_runtime.h>

// GraphSAGE 2-layer. Gathers: bf16 tables, fp32 accum, 4 chains/wave,
// <=8 distinct rows per VMEM instr, and (R12) SOFTWARE-PIPELINED index
// loads: esrc for iteration i+1 prefetched while iteration i's row loads
// are in flight -- breaks the dependent idx->row 2-load chain that was
// serializing each iteration. GEMMs: bf16 MFMA 16x16x32.
// mean(x)@W == mean(x@W): layer-2 gathers 64B rows of t2=bf16(h@Wn2).
// Pipeline: memset cursor; k_partition (+cvt feat->bf16, +weight transpose);
// k_bucket_csr (LDS counting sort); k_gather_b64 -> meanh; k_gemm_mfma
// (both layers' transforms, h LDS-resident); k_gather_b32add (out += mean).
// NOTE: harness re-poisons d_ws (268MB) each iter = fixed ~44us in dur_us.

#define SPAN        128
#define SPAN_SHIFT  7
#define PART_BLOCK  1024
#define PART_EPT    4
#define NBMAX       1024
#define LDS_S       72

typedef __attribute__((ext_vector_type(8))) short bf16x8;
typedef __attribute__((ext_vector_type(4))) float f32x4;

__device__ __forceinline__ unsigned bf16_rne(float f) {
    unsigned u = __float_as_uint(f);
    return (u + 0x7FFFu + ((u >> 16) & 1u)) >> 16;
}
__device__ __forceinline__ float bf_lo(unsigned u) { return __uint_as_float(u << 16); }
__device__ __forceinline__ float bf_hi(unsigned u) { return __uint_as_float(u & 0xFFFF0000u); }

// Partition + feat->bf16 cvt + weight transpose.
// wt layout: [mat][c][k] bf16, mat0=Ws1^T, mat1=Wn1^T, mat2=[Wn2|Ws2]^T.
__global__ __launch_bounds__(PART_BLOCK) void k_partition(
    const int* __restrict__ src, const int* __restrict__ dst,
    int* __restrict__ cursor, unsigned int* __restrict__ pairs,
    int E, int cap,
    const float* __restrict__ feat, unsigned short* __restrict__ xh, long total8,
    const float* __restrict__ ws1, const float* __restrict__ wn1,
    const float* __restrict__ ws2, const float* __restrict__ wn2,
    unsigned short* __restrict__ wt)
{
    const int tid = threadIdx.x;
    for (long i = (long)blockIdx.x * PART_BLOCK + tid; i < total8;
         i += (long)gridDim.x * PART_BLOCK) {
        const float4 a = ((const float4*)feat)[i * 2];
        const float4 b = ((const float4*)feat)[i * 2 + 1];
        uint4 o;
        o.x = bf16_rne(a.x) | (bf16_rne(a.y) << 16);
        o.y = bf16_rne(a.z) | (bf16_rne(a.w) << 16);
        o.z = bf16_rne(b.x) | (bf16_rne(b.y) << 16);
        o.w = bf16_rne(b.z) | (bf16_rne(b.w) << 16);
        ((uint4*)xh)[i] = o;
    }
    if (blockIdx.x < 12) {
        int j = blockIdx.x * PART_BLOCK + tid;   // < 12288
        int mat = j >> 12, rem = j & 4095;
        int c = rem >> 6, k = rem & 63;
        float v;
        if (mat == 0)      v = ws1[k * 64 + c];
        else if (mat == 1) v = wn1[k * 64 + c];
        else               v = (c < 32) ? wn2[k * 32 + c] : ws2[k * 32 + (c - 32)];
        wt[(mat << 12) + (c << 6) + k] = (unsigned short)bf16_rne(v);
    }

    __shared__ int cnt[NBMAX];
    __shared__ int gbase[NBMAX];
    __shared__ int lcur[NBMAX];
    cnt[tid] = 0; lcur[tid] = 0;
    __syncthreads();

    int sv[PART_EPT], bv[PART_EPT];
    const int e0 = blockIdx.x * (PART_BLOCK * PART_EPT) + tid;
    #pragma unroll
    for (int j = 0; j < PART_EPT; ++j) {
        int e = e0 + j * PART_BLOCK;
        bv[j] = -1;
        if (e < E) {
            int s = src[e], d = dst[e];
            bv[j] = d >> SPAN_SHIFT;
            sv[j] = s | ((d & (SPAN - 1)) << 24);
            atomicAdd(&cnt[bv[j]], 1);
        }
    }
    __syncthreads();
    if (cnt[tid] > 0) gbase[tid] = atomicAdd(&cursor[tid], cnt[tid]);
    __syncthreads();
    #pragma unroll
    for (int j = 0; j < PART_EPT; ++j) {
        if (bv[j] >= 0) {
            int r = gbase[bv[j]] + atomicAdd(&lcur[bv[j]], 1);
            if (r < cap) pairs[(size_t)bv[j] * cap + r] = (unsigned int)sv[j];
        }
    }
}

// Per bucket: LDS counting sort by dlocal, in-place coalesced writeback.
__global__ __launch_bounds__(256) void k_bucket_csr(
    unsigned int* __restrict__ pairs,
    const int* __restrict__ cursor,
    int* __restrict__ starts, int* __restrict__ degs,
    int N, int cap)
{
    __shared__ int cnt[SPAN];
    __shared__ int pref[SPAN];
    __shared__ int lcur[SPAN];
    extern __shared__ unsigned int sorted[];
    const int tid = threadIdx.x;
    const int b = blockIdx.x;
    if (tid < SPAN) { cnt[tid] = 0; lcur[tid] = 0; }
    __syncthreads();

    int m = cursor[b]; if (m > cap) m = cap;
    const size_t pb = (size_t)b * cap;

    for (int i = tid; i < m; i += 256)
        atomicAdd(&cnt[pairs[pb + i] >> 24], 1);
    __syncthreads();

    if (tid < SPAN) pref[tid] = cnt[tid];
    __syncthreads();
    for (int off = 1; off < SPAN; off <<= 1) {
        int v = 0;
        if (tid < SPAN && tid >= off) v = pref[tid - off];
        __syncthreads();
        if (tid < SPAN) pref[tid] += v;
        __syncthreads();
    }

    for (int i = tid; i < m; i += 256) {
        unsigned int p = pairs[pb + i];
        int r = p >> 24;
        int base = (r == 0) ? 0 : pref[r - 1];
        int pos = base + atomicAdd(&lcur[r], 1);
        sorted[pos] = p & 0xFFFFFFu;
    }
    __syncthreads();
    for (int i = tid; i < m; i += 256) pairs[pb + i] = sorted[i];
    if (tid < SPAN) {
        int node = (b << SPAN_SHIFT) + tid;
        if (node < N) {
            int base = (tid == 0) ? 0 : pref[tid - 1];
            starts[node] = (int)pb + base;
            degs[node]   = cnt[tid];
        }
    }
}

// 4 nodes/wave, pipelined: row loads for iter i overlap esrc prefetch for
// iter i+1. Per row-load: 8 slots x (8 lanes x 16B) = 8 rows / 1KB.
__global__ __launch_bounds__(256) void k_gather_b64(
    const unsigned short* __restrict__ xh,
    const unsigned int* __restrict__ esrc,
    const int* __restrict__ starts, const int* __restrict__ degs,
    unsigned short* __restrict__ meanh, int n)
{
    const int w = threadIdx.x >> 6, lane = threadIdx.x & 63;
    const int g = lane >> 3, c = lane & 7;
    const int v0 = (blockIdx.x * 4 + w) * 4;
    if (v0 >= n) return;

    int e[4], end[4], deg[4], s_cur[4];
    #pragma unroll
    for (int j = 0; j < 4; ++j) {
        int v = v0 + j;
        if (v < n) { int b = starts[v]; deg[j] = degs[v]; e[j] = b + g; end[j] = b + deg[j]; }
        else { deg[j] = 0; e[j] = 0; end[j] = 0; }
    }
    #pragma unroll
    for (int j = 0; j < 4; ++j) {
        int idx = (e[j] < end[j]) ? e[j] : 0;
        int s = (int)(esrc[idx] & 0xFFFFFFu);
        s_cur[j] = s < n ? s : n - 1;
    }
    float acc[4][8];
    #pragma unroll
    for (int j = 0; j < 4; ++j)
        #pragma unroll
        for (int k = 0; k < 8; ++k) acc[j][k] = 0.f;

    bool any = (e[0] < end[0]) | (e[1] < end[1]) | (e[2] < end[2]) | (e[3] < end[3]);
    while (any) {
        uint4 u[4]; float m[4];
        #pragma unroll
        for (int j = 0; j < 4; ++j) {
            m[j] = (e[j] < end[j]) ? 1.f : 0.f;
            u[j] = *(const uint4*)&xh[(size_t)s_cur[j] * 64 + c * 8];
        }
        // advance + prefetch next indices (overlaps the row loads above)
        #pragma unroll
        for (int j = 0; j < 4; ++j) e[j] += 8;
        any = (e[0] < end[0]) | (e[1] < end[1]) | (e[2] < end[2]) | (e[3] < end[3]);
        #pragma unroll
        for (int j = 0; j < 4; ++j) {
            int idx = (e[j] < end[j]) ? e[j] : 0;
            int s = (int)(esrc[idx] & 0xFFFFFFu);
            s_cur[j] = s < n ? s : n - 1;
        }
        #pragma unroll
        for (int j = 0; j < 4; ++j) {
            acc[j][0] = fmaf(m[j], bf_lo(u[j].x), acc[j][0]);
            acc[j][1] = fmaf(m[j], bf_hi(u[j].x), acc[j][1]);
            acc[j][2] = fmaf(m[j], bf_lo(u[j].y), acc[j][2]);
            acc[j][3] = fmaf(m[j], bf_hi(u[j].y), acc[j][3]);
            acc[j][4] = fmaf(m[j], bf_lo(u[j].z), acc[j][4]);
            acc[j][5] = fmaf(m[j], bf_hi(u[j].z), acc[j][5]);
            acc[j][6] = fmaf(m[j], bf_lo(u[j].w), acc[j][6]);
            acc[j][7] = fmaf(m[j], bf_hi(u[j].w), acc[j][7]);
        }
    }
    #pragma unroll
    for (int j = 0; j < 4; ++j) {
        #pragma unroll
        for (int d = 8; d <= 32; d <<= 1) {
            #pragma unroll
            for (int k = 0; k < 8; ++k) acc[j][k] += __shfl_xor(acc[j][k], d);
        }
        if (lane < 8 && v0 + j < n) {
            float f = deg[j] ? 1.f / (float)deg[j] : 0.f;
            uint4 o;
            o.x = bf16_rne(acc[j][0] * f) | (bf16_rne(acc[j][1] * f) << 16);
            o.y = bf16_rne(acc[j][2] * f) | (bf16_rne(acc[j][3] * f) << 16);
            o.z = bf16_rne(acc[j][4] * f) | (bf16_rne(acc[j][5] * f) << 16);
            o.w = bf16_rne(acc[j][6] * f) | (bf16_rne(acc[j][7] * f) << 16);
            *(uint4*)&meanh[(size_t)(v0 + j) * 64 + c * 8] = o;
        }
    }
}

// MFMA GEMM: 128-row tile, 4 waves, each wave 32 rows x 64 cols.
__global__ __launch_bounds__(256) void k_gemm_mfma(
    const unsigned short* __restrict__ xh,     // [N,64] bf16
    const unsigned short* __restrict__ meanh,  // [N,64] bf16
    const unsigned short* __restrict__ wt,     // [3][64][64] bf16 c-major
    const float* __restrict__ b1, const float* __restrict__ b2,
    unsigned short* __restrict__ t2,           // [N,32] bf16
    float* __restrict__ outp,                  // [N,32] f32
    int n)
{
    __shared__ __align__(16) unsigned short sX[128 * LDS_S];
    __shared__ __align__(16) unsigned short sWt[3 * 64 * LDS_S];
    const int tid  = threadIdx.x;
    const int w    = tid >> 6, lane = tid & 63;
    const int quad = lane >> 4, lm = lane & 15;
    const int gm0  = blockIdx.x * 128;
    const int rowA = w * 32;

    for (int i = tid; i < 1536; i += 256) {
        int r  = i >> 3;
        int k0 = (i & 7) << 3;
        *(uint4*)&sWt[r * LDS_S + k0] = *(const uint4*)&wt[(r << 6) + k0];
    }
    for (int i = tid; i < 1024; i += 256) {
        int m = i >> 3, k0 = (i & 7) << 3;
        int gm = gm0 + m;
        uint4 v = make_uint4(0, 0, 0, 0);
        if (gm < n) v = *(const uint4*)&xh[(size_t)gm * 64 + k0];
        *(uint4*)&sX[m * LDS_S + k0] = v;
    }
    __syncthreads();

    f32x4 acc[2][4];
    #pragma unroll
    for (int mt = 0; mt < 2; ++mt)
        #pragma unroll
        for (int nt = 0; nt < 4; ++nt) acc[mt][nt] = (f32x4){0.f, 0.f, 0.f, 0.f};

    #pragma unroll
    for (int kt = 0; kt < 2; ++kt) {
        bf16x8 a0 = *(const bf16x8*)&sX[(rowA + lm) * LDS_S + kt * 32 + quad * 8];
        bf16x8 a1 = *(const bf16x8*)&sX[(rowA + 16 + lm) * LDS_S + kt * 32 + quad * 8];
        #pragma unroll
        for (int nt = 0; nt < 4; ++nt) {
            bf16x8 b = *(const bf16x8*)&sWt[(nt * 16 + lm) * LDS_S + kt * 32 + quad * 8];
            acc[0][nt] = __builtin_amdgcn_mfma_f32_16x16x32_bf16(a0, b, acc[0][nt], 0, 0, 0);
            acc[1][nt] = __builtin_amdgcn_mfma_f32_16x16x32_bf16(a1, b, acc[1][nt], 0, 0, 0);
        }
    }
    __syncthreads();
    for (int i = tid; i < 1024; i += 256) {
        int m = i >> 3, k0 = (i & 7) << 3;
        int gm = gm0 + m;
        uint4 v = make_uint4(0, 0, 0, 0);
        if (gm < n) v = *(const uint4*)&meanh[(size_t)gm * 64 + k0];
        *(uint4*)&sX[m * LDS_S + k0] = v;
    }
    __syncthreads();
    #pragma unroll
    for (int kt = 0; kt < 2; ++kt) {
        bf16x8 a0 = *(const bf16x8*)&sX[(rowA + lm) * LDS_S + kt * 32 + quad * 8];
        bf16x8 a1 = *(const bf16x8*)&sX[(rowA + 16 + lm) * LDS_S + kt * 32 + quad * 8];
        #pragma unroll
        for (int nt = 0; nt < 4; ++nt) {
            bf16x8 b = *(const bf16x8*)&sWt[(64 + nt * 16 + lm) * LDS_S + kt * 32 + quad * 8];
            acc[0][nt] = __builtin_amdgcn_mfma_f32_16x16x32_bf16(a0, b, acc[0][nt], 0, 0, 0);
            acc[1][nt] = __builtin_amdgcn_mfma_f32_16x16x32_bf16(a1, b, acc[1][nt], 0, 0, 0);
        }
    }
    __syncthreads();

    #pragma unroll
    for (int nt = 0; nt < 4; ++nt) {
        float bb = b1[nt * 16 + lm];
        #pragma unroll
        for (int mt = 0; mt < 2; ++mt) {
            int rbase = rowA + mt * 16 + quad * 4;
            #pragma unroll
            for (int r = 0; r < 4; ++r) {
                float hv = fmaxf(acc[mt][nt][r] + bb, 0.f);
                sX[(rbase + r) * LDS_S + nt * 16 + lm] = (unsigned short)bf16_rne(hv);
            }
        }
    }

    f32x4 acc2[2][4];
    #pragma unroll
    for (int mt = 0; mt < 2; ++mt)
        #pragma unroll
        for (int nt = 0; nt < 4; ++nt) acc2[mt][nt] = (f32x4){0.f, 0.f, 0.f, 0.f};
    #pragma unroll
    for (int kt = 0; kt < 2; ++kt) {
        bf16x8 a0 = *(const bf16x8*)&sX[(rowA + lm) * LDS_S + kt * 32 + quad * 8];
        bf16x8 a1 = *(const bf16x8*)&sX[(rowA + 16 + lm) * LDS_S + kt * 32 + quad * 8];
        #pragma unroll
        for (int nt = 0; nt < 4; ++nt) {
            bf16x8 b = *(const bf16x8*)&sWt[(128 + nt * 16 + lm) * LDS_S + kt * 32 + quad * 8];
            acc2[0][nt] = __builtin_amdgcn_mfma_f32_16x16x32_bf16(a0, b, acc2[0][nt], 0, 0, 0);
            acc2[1][nt] = __builtin_amdgcn_mfma_f32_16x16x32_bf16(a1, b, acc2[1][nt], 0, 0, 0);
        }
    }

    #pragma unroll
    for (int mt = 0; mt < 2; ++mt) {
        int rbase = gm0 + rowA + mt * 16 + quad * 4;
        #pragma unroll
        for (int nt = 0; nt < 2; ++nt) {
            #pragma unroll
            for (int r = 0; r < 4; ++r) {
                int gm = rbase + r;
                if (gm < n)
                    t2[(size_t)gm * 32 + nt * 16 + lm] =
                        (unsigned short)bf16_rne(acc2[mt][nt][r]);
            }
        }
        #pragma unroll
        for (int nt = 2; nt < 4; ++nt) {
            float bb = b2[(nt - 2) * 16 + lm];
            #pragma unroll
            for (int r = 0; r < 4; ++r) {
                int gm = rbase + r;
                if (gm < n)
                    outp[(size_t)gm * 32 + (nt - 2) * 16 + lm] = acc2[mt][nt][r] + bb;
            }
        }
    }
}

// 4 nodes/wave, pipelined index prefetch; 8 slots x (8 lanes x uint2 8B)
// = 8 rows / 512B per instr. out += mean(t2 rows).
__global__ __launch_bounds__(256) void k_gather_b32add(
    const unsigned short* __restrict__ t2,
    const unsigned int* __restrict__ esrc,
    const int* __restrict__ starts, const int* __restrict__ degs,
    float* __restrict__ outp, int n)
{
    const int w = threadIdx.x >> 6, lane = threadIdx.x & 63;
    const int g = lane >> 3, c = lane & 7;     // 8 slots x 8 chunks(4 bf16)
    const int v0 = (blockIdx.x * 4 + w) * 4;
    if (v0 >= n) return;

    int e[4], end[4], deg[4], s_cur[4];
    #pragma unroll
    for (int j = 0; j < 4; ++j) {
        int v = v0 + j;
        if (v < n) { int b = starts[v]; deg[j] = degs[v]; e[j] = b + g; end[j] = b + deg[j]; }
        else { deg[j] = 0; e[j] = 0; end[j] = 0; }
    }
    #pragma unroll
    for (int j = 0; j < 4; ++j) {
        int idx = (e[j] < end[j]) ? e[j] : 0;
        int s = (int)(esrc[idx] & 0xFFFFFFu);
        s_cur[j] = s < n ? s : n - 1;
    }
    float acc[4][4];
    #pragma unroll
    for (int j = 0; j < 4; ++j)
        #pragma unroll
        for (int k = 0; k < 4; ++k) acc[j][k] = 0.f;

    bool any = (e[0] < end[0]) | (e[1] < end[1]) | (e[2] < end[2]) | (e[3] < end[3]);
    while (any) {
        uint2 u[4]; float m[4];
        #pragma unroll
        for (int j = 0; j < 4; ++j) {
            m[j] = (e[j] < end[j]) ? 1.f : 0.f;
            u[j] = *(const uint2*)&t2[(size_t)s_cur[j] * 32 + c * 4];
        }
        #pragma unroll
        for (int j = 0; j < 4; ++j) e[j] += 8;
        any = (e[0] < end[0]) | (e[1] < end[1]) | (e[2] < end[2]) | (e[3] < end[3]);
        #pragma unroll
        for (int j = 0; j < 4; ++j) {
            int idx = (e[j] < end[j]) ? e[j] : 0;
            int s = (int)(esrc[idx] & 0xFFFFFFu);
            s_cur[j] = s < n ? s : n - 1;
        }
        #pragma unroll
        for (int j = 0; j < 4; ++j) {
            acc[j][0] = fmaf(m[j], bf_lo(u[j].x), acc[j][0]);
            acc[j][1] = fmaf(m[j], bf_hi(u[j].x), acc[j][1]);
            acc[j][2] = fmaf(m[j], bf_lo(u[j].y), acc[j][2]);
            acc[j][3] = fmaf(m[j], bf_hi(u[j].y), acc[j][3]);
        }
    }
    #pragma unroll
    for (int j = 0; j < 4; ++j) {
        #pragma unroll
        for (int d = 8; d <= 32; d <<= 1) {
            #pragma unroll
            for (int k = 0; k < 4; ++k) acc[j][k] += __shfl_xor(acc[j][k], d);
        }
        if (lane < 8 && v0 + j < n && deg[j] > 0) {
            float f = 1.f / (float)deg[j];
            float4 o = *(const float4*)&outp[(size_t)(v0 + j) * 32 + c * 4];
            o.x += acc[j][0] * f; o.y += acc[j][1] * f;
            o.z += acc[j][2] * f; o.w += acc[j][3] * f;
            *(float4*)&outp[(size_t)(v0 + j) * 32 + c * 4] = o;
        }
    }
}

extern "C" void kernel_launch(void* const* d_in, const int* in_sizes, int n_in,
                              void* d_out, int out_size, void* d_ws, size_t ws_size,
                              hipStream_t stream) {
    const float* feat = (const float*)d_in[0];
    const int*   src  = (const int*)d_in[1];
    const int*   dst  = (const int*)d_in[2];
    const float* ws1  = (const float*)d_in[3];
    const float* wn1  = (const float*)d_in[4];
    const float* b1   = (const float*)d_in[5];
    const float* ws2  = (const float*)d_in[6];
    const float* wn2  = (const float*)d_in[7];
    const float* b2   = (const float*)d_in[8];
    float* out = (float*)d_out;

    const int N = in_sizes[0] / 64;
    const int E = in_sizes[1];
    const int nB = (N + SPAN - 1) >> SPAN_SHIFT;

    int cap = ((E + nB - 1) / nB);
    cap = ((cap + cap / 4) + 63) & ~63;
    {
        size_t fixedBytes = NBMAX * 4 + 3 * 4096 * 2 + (size_t)N * 8
                          + (size_t)N * 64 * 2 * 2   // meanh + xh
                          + (size_t)N * 32 * 2       // t2
                          + 16384;
        size_t remain = (ws_size > fixedBytes) ? (ws_size - fixedBytes) : 0;
        size_t capMax = remain / ((size_t)nB * 4);
        if ((size_t)cap > capMax) cap = (int)(capMax & ~(size_t)3);
    }

    char* base = (char*)d_ws;
    int* cursor = (int*)base;                                    // [1024]
    unsigned short* wt = (unsigned short*)(base + NBMAX * 4);    // [3][64][64] bf16
    unsigned int* pairs = (unsigned int*)(base + NBMAX * 4 + 24576);
    size_t sOff = ((size_t)NBMAX * 4 + 24576 + (size_t)nB * cap * 4 + 4096 + 255) & ~(size_t)255;
    int* starts = (int*)(base + sOff);                           // [N]
    int* degs   = starts + N;                                    // [N]
    size_t mOff = (sOff + (size_t)N * 8 + 255) & ~(size_t)255;
    unsigned short* meanh = (unsigned short*)(base + mOff);      // [N,64] bf16
    unsigned short* xh    = meanh + (size_t)N * 64;              // [N,64] bf16
    unsigned short* t2    = xh + (size_t)N * 64;                 // [N,32] bf16

    hipMemsetAsync(cursor, 0, NBMAX * 4, stream);

    const long total8 = (long)N * 64 / 8;
    const int pblocks = (E + PART_BLOCK * PART_EPT - 1) / (PART_BLOCK * PART_EPT);
    k_partition<<<pblocks, PART_BLOCK, 0, stream>>>(
        src, dst, cursor, pairs, E, cap,
        feat, xh, total8, ws1, wn1, ws2, wn2, wt);
    k_bucket_csr<<<nB, 256, (size_t)cap * 4, stream>>>(pairs, cursor, starts, degs, N, cap);

    const int gblocks = (N + 15) / 16;   // 16 nodes per block (4/wave)
    const int tblocks = (N + 127) / 128;

    k_gather_b64<<<gblocks, 256, 0, stream>>>(xh, pairs, starts, degs, meanh, N);
    k_gemm_mfma<<<tblocks, 256, 0, stream>>>(xh, meanh, wt, b1, b2, t2, out, N);
    k_gather_b32add<<<gblocks, 256, 0, stream>>>(t2, pairs, starts, degs, out, N);
}

// Round 13
// 180.798 us; speedup vs baseline: 1.0899x; 1.0899x over previous
//
#include <hip/hip_runtime.h>

// GraphSAGE 2-layer. Gathers: bf16 tables, fp32 accum, 4 chains/wave,
// <=8 distinct rows per VMEM instr, simple in-loop index load (R12's
// prefetch pipelining ADDED critical-path VALU and regressed - reverted).
// R13: gather_b64 uses 4 slots x 16 lanes x 8B (512B/instr): Poisson(10)
// degrees waste 29% of 8-slot iterations; 4-slot cuts issued bytes 21%.
// GEMMs: bf16 MFMA 16x16x32. mean(x)@W == mean(x@W): layer-2 gathers 64B
// rows of t2=bf16(h@Wn2).
// Pipeline: memset cursor; k_partition (+cvt feat->bf16, +weight transpose);
// k_bucket_csr (LDS counting sort); k_gather_b64 -> meanh; k_gemm_mfma
// (both layers' transforms, h LDS-resident); k_gather_b32add (out += mean).
// NOTE: harness re-poisons d_ws (268MB) each iter = fixed ~44us in dur_us.

#define SPAN        128
#define SPAN_SHIFT  7
#define PART_BLOCK  1024
#define PART_EPT    4
#define NBMAX       1024
#define LDS_S       72

typedef __attribute__((ext_vector_type(8))) short bf16x8;
typedef __attribute__((ext_vector_type(4))) float f32x4;

__device__ __forceinline__ unsigned bf16_rne(float f) {
    unsigned u = __float_as_uint(f);
    return (u + 0x7FFFu + ((u >> 16) & 1u)) >> 16;
}
__device__ __forceinline__ float bf_lo(unsigned u) { return __uint_as_float(u << 16); }
__device__ __forceinline__ float bf_hi(unsigned u) { return __uint_as_float(u & 0xFFFF0000u); }

// Partition + feat->bf16 cvt + weight transpose.
// wt layout: [mat][c][k] bf16, mat0=Ws1^T, mat1=Wn1^T, mat2=[Wn2|Ws2]^T.
__global__ __launch_bounds__(PART_BLOCK) void k_partition(
    const int* __restrict__ src, const int* __restrict__ dst,
    int* __restrict__ cursor, unsigned int* __restrict__ pairs,
    int E, int cap,
    const float* __restrict__ feat, unsigned short* __restrict__ xh, long total8,
    const float* __restrict__ ws1, const float* __restrict__ wn1,
    const float* __restrict__ ws2, const float* __restrict__ wn2,
    unsigned short* __restrict__ wt)
{
    const int tid = threadIdx.x;
    for (long i = (long)blockIdx.x * PART_BLOCK + tid; i < total8;
         i += (long)gridDim.x * PART_BLOCK) {
        const float4 a = ((const float4*)feat)[i * 2];
        const float4 b = ((const float4*)feat)[i * 2 + 1];
        uint4 o;
        o.x = bf16_rne(a.x) | (bf16_rne(a.y) << 16);
        o.y = bf16_rne(a.z) | (bf16_rne(a.w) << 16);
        o.z = bf16_rne(b.x) | (bf16_rne(b.y) << 16);
        o.w = bf16_rne(b.z) | (bf16_rne(b.w) << 16);
        ((uint4*)xh)[i] = o;
    }
    if (blockIdx.x < 12) {
        int j = blockIdx.x * PART_BLOCK + tid;   // < 12288
        int mat = j >> 12, rem = j & 4095;
        int c = rem >> 6, k = rem & 63;
        float v;
        if (mat == 0)      v = ws1[k * 64 + c];
        else if (mat == 1) v = wn1[k * 64 + c];
        else               v = (c < 32) ? wn2[k * 32 + c] : ws2[k * 32 + (c - 32)];
        wt[(mat << 12) + (c << 6) + k] = (unsigned short)bf16_rne(v);
    }

    __shared__ int cnt[NBMAX];
    __shared__ int gbase[NBMAX];
    __shared__ int lcur[NBMAX];
    cnt[tid] = 0; lcur[tid] = 0;
    __syncthreads();

    int sv[PART_EPT], bv[PART_EPT];
    const int e0 = blockIdx.x * (PART_BLOCK * PART_EPT) + tid;
    #pragma unroll
    for (int j = 0; j < PART_EPT; ++j) {
        int e = e0 + j * PART_BLOCK;
        bv[j] = -1;
        if (e < E) {
            int s = src[e], d = dst[e];
            bv[j] = d >> SPAN_SHIFT;
            sv[j] = s | ((d & (SPAN - 1)) << 24);
            atomicAdd(&cnt[bv[j]], 1);
        }
    }
    __syncthreads();
    if (cnt[tid] > 0) gbase[tid] = atomicAdd(&cursor[tid], cnt[tid]);
    __syncthreads();
    #pragma unroll
    for (int j = 0; j < PART_EPT; ++j) {
        if (bv[j] >= 0) {
            int r = gbase[bv[j]] + atomicAdd(&lcur[bv[j]], 1);
            if (r < cap) pairs[(size_t)bv[j] * cap + r] = (unsigned int)sv[j];
        }
    }
}

// Per bucket: LDS counting sort by dlocal, in-place coalesced writeback.
__global__ __launch_bounds__(256) void k_bucket_csr(
    unsigned int* __restrict__ pairs,
    const int* __restrict__ cursor,
    int* __restrict__ starts, int* __restrict__ degs,
    int N, int cap)
{
    __shared__ int cnt[SPAN];
    __shared__ int pref[SPAN];
    __shared__ int lcur[SPAN];
    extern __shared__ unsigned int sorted[];
    const int tid = threadIdx.x;
    const int b = blockIdx.x;
    if (tid < SPAN) { cnt[tid] = 0; lcur[tid] = 0; }
    __syncthreads();

    int m = cursor[b]; if (m > cap) m = cap;
    const size_t pb = (size_t)b * cap;

    for (int i = tid; i < m; i += 256)
        atomicAdd(&cnt[pairs[pb + i] >> 24], 1);
    __syncthreads();

    if (tid < SPAN) pref[tid] = cnt[tid];
    __syncthreads();
    for (int off = 1; off < SPAN; off <<= 1) {
        int v = 0;
        if (tid < SPAN && tid >= off) v = pref[tid - off];
        __syncthreads();
        if (tid < SPAN) pref[tid] += v;
        __syncthreads();
    }

    for (int i = tid; i < m; i += 256) {
        unsigned int p = pairs[pb + i];
        int r = p >> 24;
        int base = (r == 0) ? 0 : pref[r - 1];
        int pos = base + atomicAdd(&lcur[r], 1);
        sorted[pos] = p & 0xFFFFFFu;
    }
    __syncthreads();
    for (int i = tid; i < m; i += 256) pairs[pb + i] = sorted[i];
    if (tid < SPAN) {
        int node = (b << SPAN_SHIFT) + tid;
        if (node < N) {
            int base = (tid == 0) ? 0 : pref[tid - 1];
            starts[node] = (int)pb + base;
            degs[node]   = cnt[tid];
        }
    }
}

// 4 nodes/wave, 4 chains; per chain-load: 4 slots x (16 lanes x uint2 8B)
// = 4 distinct rows / 512B per instr. Poisson(10) degs: 4-slot issues
// E[ceil(d/4)]*512B = 1.39KB/node vs 8-slot's 1.75KB (-21%).
__global__ __launch_bounds__(256) void k_gather_b64(
    const unsigned short* __restrict__ xh,
    const unsigned int* __restrict__ esrc,
    const int* __restrict__ starts, const int* __restrict__ degs,
    unsigned short* __restrict__ meanh, int n)
{
    const int w = threadIdx.x >> 6, lane = threadIdx.x & 63;
    const int g = lane >> 4, c = lane & 15;   // 4 slots x 16 chunks(4 bf16)
    const int v0 = (blockIdx.x * 4 + w) * 4;
    if (v0 >= n) return;

    int e[4], end[4], deg[4];
    #pragma unroll
    for (int j = 0; j < 4; ++j) {
        int v = v0 + j;
        if (v < n) { int b = starts[v]; deg[j] = degs[v]; e[j] = b + g; end[j] = b + deg[j]; }
        else { deg[j] = 0; e[j] = 0; end[j] = 0; }
    }
    float acc[4][4];
    #pragma unroll
    for (int j = 0; j < 4; ++j)
        #pragma unroll
        for (int k = 0; k < 4; ++k) acc[j][k] = 0.f;

    while ((e[0] < end[0]) | (e[1] < end[1]) | (e[2] < end[2]) | (e[3] < end[3])) {
        uint2 u[4]; float m[4];
        #pragma unroll
        for (int j = 0; j < 4; ++j) {
            bool p = e[j] < end[j];
            m[j] = p ? 1.f : 0.f;
            int idx = p ? e[j] : 0;
            int s = (int)(esrc[idx] & 0xFFFFFFu);
            s = s < n ? s : n - 1;            // clamp vs garbage slab slots
            u[j] = *(const uint2*)&xh[(size_t)s * 64 + c * 4];
        }
        #pragma unroll
        for (int j = 0; j < 4; ++j) {
            acc[j][0] = fmaf(m[j], bf_lo(u[j].x), acc[j][0]);
            acc[j][1] = fmaf(m[j], bf_hi(u[j].x), acc[j][1]);
            acc[j][2] = fmaf(m[j], bf_lo(u[j].y), acc[j][2]);
            acc[j][3] = fmaf(m[j], bf_hi(u[j].y), acc[j][3]);
            e[j] += 4;
        }
    }
    #pragma unroll
    for (int j = 0; j < 4; ++j) {
        #pragma unroll
        for (int d = 16; d <= 32; d <<= 1) {
            #pragma unroll
            for (int k = 0; k < 4; ++k) acc[j][k] += __shfl_xor(acc[j][k], d);
        }
        if (lane < 16 && v0 + j < n) {
            float f = deg[j] ? 1.f / (float)deg[j] : 0.f;
            uint2 o;
            o.x = bf16_rne(acc[j][0] * f) | (bf16_rne(acc[j][1] * f) << 16);
            o.y = bf16_rne(acc[j][2] * f) | (bf16_rne(acc[j][3] * f) << 16);
            *(uint2*)&meanh[(size_t)(v0 + j) * 64 + c * 4] = o;
        }
    }
}

// MFMA GEMM: 128-row tile, 4 waves, each wave 32 rows x 64 cols.
__global__ __launch_bounds__(256) void k_gemm_mfma(
    const unsigned short* __restrict__ xh,     // [N,64] bf16
    const unsigned short* __restrict__ meanh,  // [N,64] bf16
    const unsigned short* __restrict__ wt,     // [3][64][64] bf16 c-major
    const float* __restrict__ b1, const float* __restrict__ b2,
    unsigned short* __restrict__ t2,           // [N,32] bf16
    float* __restrict__ outp,                  // [N,32] f32
    int n)
{
    __shared__ __align__(16) unsigned short sX[128 * LDS_S];
    __shared__ __align__(16) unsigned short sWt[3 * 64 * LDS_S];
    const int tid  = threadIdx.x;
    const int w    = tid >> 6, lane = tid & 63;
    const int quad = lane >> 4, lm = lane & 15;
    const int gm0  = blockIdx.x * 128;
    const int rowA = w * 32;

    for (int i = tid; i < 1536; i += 256) {
        int r  = i >> 3;
        int k0 = (i & 7) << 3;
        *(uint4*)&sWt[r * LDS_S + k0] = *(const uint4*)&wt[(r << 6) + k0];
    }
    for (int i = tid; i < 1024; i += 256) {
        int m = i >> 3, k0 = (i & 7) << 3;
        int gm = gm0 + m;
        uint4 v = make_uint4(0, 0, 0, 0);
        if (gm < n) v = *(const uint4*)&xh[(size_t)gm * 64 + k0];
        *(uint4*)&sX[m * LDS_S + k0] = v;
    }
    __syncthreads();

    f32x4 acc[2][4];
    #pragma unroll
    for (int mt = 0; mt < 2; ++mt)
        #pragma unroll
        for (int nt = 0; nt < 4; ++nt) acc[mt][nt] = (f32x4){0.f, 0.f, 0.f, 0.f};

    #pragma unroll
    for (int kt = 0; kt < 2; ++kt) {
        bf16x8 a0 = *(const bf16x8*)&sX[(rowA + lm) * LDS_S + kt * 32 + quad * 8];
        bf16x8 a1 = *(const bf16x8*)&sX[(rowA + 16 + lm) * LDS_S + kt * 32 + quad * 8];
        #pragma unroll
        for (int nt = 0; nt < 4; ++nt) {
            bf16x8 b = *(const bf16x8*)&sWt[(nt * 16 + lm) * LDS_S + kt * 32 + quad * 8];
            acc[0][nt] = __builtin_amdgcn_mfma_f32_16x16x32_bf16(a0, b, acc[0][nt], 0, 0, 0);
            acc[1][nt] = __builtin_amdgcn_mfma_f32_16x16x32_bf16(a1, b, acc[1][nt], 0, 0, 0);
        }
    }
    __syncthreads();
    for (int i = tid; i < 1024; i += 256) {
        int m = i >> 3, k0 = (i & 7) << 3;
        int gm = gm0 + m;
        uint4 v = make_uint4(0, 0, 0, 0);
        if (gm < n) v = *(const uint4*)&meanh[(size_t)gm * 64 + k0];
        *(uint4*)&sX[m * LDS_S + k0] = v;
    }
    __syncthreads();
    #pragma unroll
    for (int kt = 0; kt < 2; ++kt) {
        bf16x8 a0 = *(const bf16x8*)&sX[(rowA + lm) * LDS_S + kt * 32 + quad * 8];
        bf16x8 a1 = *(const bf16x8*)&sX[(rowA + 16 + lm) * LDS_S + kt * 32 + quad * 8];
        #pragma unroll
        for (int nt = 0; nt < 4; ++nt) {
            bf16x8 b = *(const bf16x8*)&sWt[(64 + nt * 16 + lm) * LDS_S + kt * 32 + quad * 8];
            acc[0][nt] = __builtin_amdgcn_mfma_f32_16x16x32_bf16(a0, b, acc[0][nt], 0, 0, 0);
            acc[1][nt] = __builtin_amdgcn_mfma_f32_16x16x32_bf16(a1, b, acc[1][nt], 0, 0, 0);
        }
    }
    __syncthreads();

    #pragma unroll
    for (int nt = 0; nt < 4; ++nt) {
        float bb = b1[nt * 16 + lm];
        #pragma unroll
        for (int mt = 0; mt < 2; ++mt) {
            int rbase = rowA + mt * 16 + quad * 4;
            #pragma unroll
            for (int r = 0; r < 4; ++r) {
                float hv = fmaxf(acc[mt][nt][r] + bb, 0.f);
                sX[(rbase + r) * LDS_S + nt * 16 + lm] = (unsigned short)bf16_rne(hv);
            }
        }
    }

    f32x4 acc2[2][4];
    #pragma unroll
    for (int mt = 0; mt < 2; ++mt)
        #pragma unroll
        for (int nt = 0; nt < 4; ++nt) acc2[mt][nt] = (f32x4){0.f, 0.f, 0.f, 0.f};
    #pragma unroll
    for (int kt = 0; kt < 2; ++kt) {
        bf16x8 a0 = *(const bf16x8*)&sX[(rowA + lm) * LDS_S + kt * 32 + quad * 8];
        bf16x8 a1 = *(const bf16x8*)&sX[(rowA + 16 + lm) * LDS_S + kt * 32 + quad * 8];
        #pragma unroll
        for (int nt = 0; nt < 4; ++nt) {
            bf16x8 b = *(const bf16x8*)&sWt[(128 + nt * 16 + lm) * LDS_S + kt * 32 + quad * 8];
            acc2[0][nt] = __builtin_amdgcn_mfma_f32_16x16x32_bf16(a0, b, acc2[0][nt], 0, 0, 0);
            acc2[1][nt] = __builtin_amdgcn_mfma_f32_16x16x32_bf16(a1, b, acc2[1][nt], 0, 0, 0);
        }
    }

    #pragma unroll
    for (int mt = 0; mt < 2; ++mt) {
        int rbase = gm0 + rowA + mt * 16 + quad * 4;
        #pragma unroll
        for (int nt = 0; nt < 2; ++nt) {
            #pragma unroll
            for (int r = 0; r < 4; ++r) {
                int gm = rbase + r;
                if (gm < n)
                    t2[(size_t)gm * 32 + nt * 16 + lm] =
                        (unsigned short)bf16_rne(acc2[mt][nt][r]);
            }
        }
        #pragma unroll
        for (int nt = 2; nt < 4; ++nt) {
            float bb = b2[(nt - 2) * 16 + lm];
            #pragma unroll
            for (int r = 0; r < 4; ++r) {
                int gm = rbase + r;
                if (gm < n)
                    outp[(size_t)gm * 32 + (nt - 2) * 16 + lm] = acc2[mt][nt][r] + bb;
            }
        }
    }
}

// 4 nodes/wave, 4 chains; 8 slots x (8 lanes x uint2 8B) = 8 rows / 512B
// per instr (R11-proven shape). out += mean(t2 rows).
__global__ __launch_bounds__(256) void k_gather_b32add(
    const unsigned short* __restrict__ t2,
    const unsigned int* __restrict__ esrc,
    const int* __restrict__ starts, const int* __restrict__ degs,
    float* __restrict__ outp, int n)
{
    const int w = threadIdx.x >> 6, lane = threadIdx.x & 63;
    const int g = lane >> 3, c = lane & 7;     // 8 slots x 8 chunks(4 bf16)
    const int v0 = (blockIdx.x * 4 + w) * 4;
    if (v0 >= n) return;

    int e[4], end[4], deg[4];
    #pragma unroll
    for (int j = 0; j < 4; ++j) {
        int v = v0 + j;
        if (v < n) { int b = starts[v]; deg[j] = degs[v]; e[j] = b + g; end[j] = b + deg[j]; }
        else { deg[j] = 0; e[j] = 0; end[j] = 0; }
    }
    float acc[4][4];
    #pragma unroll
    for (int j = 0; j < 4; ++j)
        #pragma unroll
        for (int k = 0; k < 4; ++k) acc[j][k] = 0.f;

    while ((e[0] < end[0]) | (e[1] < end[1]) | (e[2] < end[2]) | (e[3] < end[3])) {
        uint2 u[4]; float m[4];
        #pragma unroll
        for (int j = 0; j < 4; ++j) {
            bool p = e[j] < end[j];
            m[j] = p ? 1.f : 0.f;
            int idx = p ? e[j] : 0;
            int s = (int)(esrc[idx] & 0xFFFFFFu);
            s = s < n ? s : n - 1;
            u[j] = *(const uint2*)&t2[(size_t)s * 32 + c * 4];
        }
        #pragma unroll
        for (int j = 0; j < 4; ++j) {
            acc[j][0] = fmaf(m[j], bf_lo(u[j].x), acc[j][0]);
            acc[j][1] = fmaf(m[j], bf_hi(u[j].x), acc[j][1]);
            acc[j][2] = fmaf(m[j], bf_lo(u[j].y), acc[j][2]);
            acc[j][3] = fmaf(m[j], bf_hi(u[j].y), acc[j][3]);
            e[j] += 8;
        }
    }
    #pragma unroll
    for (int j = 0; j < 4; ++j) {
        #pragma unroll
        for (int d = 8; d <= 32; d <<= 1) {
            #pragma unroll
            for (int k = 0; k < 4; ++k) acc[j][k] += __shfl_xor(acc[j][k], d);
        }
        if (lane < 8 && v0 + j < n && deg[j] > 0) {
            float f = 1.f / (float)deg[j];
            float4 o = *(const float4*)&outp[(size_t)(v0 + j) * 32 + c * 4];
            o.x += acc[j][0] * f; o.y += acc[j][1] * f;
            o.z += acc[j][2] * f; o.w += acc[j][3] * f;
            *(float4*)&outp[(size_t)(v0 + j) * 32 + c * 4] = o;
        }
    }
}

extern "C" void kernel_launch(void* const* d_in, const int* in_sizes, int n_in,
                              void* d_out, int out_size, void* d_ws, size_t ws_size,
                              hipStream_t stream) {
    const float* feat = (const float*)d_in[0];
    const int*   src  = (const int*)d_in[1];
    const int*   dst  = (const int*)d_in[2];
    const float* ws1  = (const float*)d_in[3];
    const float* wn1  = (const float*)d_in[4];
    const float* b1   = (const float*)d_in[5];
    const float* ws2  = (const float*)d_in[6];
    const float* wn2  = (const float*)d_in[7];
    const float* b2   = (const float*)d_in[8];
    float* out = (float*)d_out;

    const int N = in_sizes[0] / 64;
    const int E = in_sizes[1];
    const int nB = (N + SPAN - 1) >> SPAN_SHIFT;

    int cap = ((E + nB - 1) / nB);
    cap = ((cap + cap / 4) + 63) & ~63;
    {
        size_t fixedBytes = NBMAX * 4 + 3 * 4096 * 2 + (size_t)N * 8
                          + (size_t)N * 64 * 2 * 2   // meanh + xh
                          + (size_t)N * 32 * 2       // t2
                          + 16384;
        size_t remain = (ws_size > fixedBytes) ? (ws_size - fixedBytes) : 0;
        size_t capMax = remain / ((size_t)nB * 4);
        if ((size_t)cap > capMax) cap = (int)(capMax & ~(size_t)3);
    }

    char* base = (char*)d_ws;
    int* cursor = (int*)base;                                    // [1024]
    unsigned short* wt = (unsigned short*)(base + NBMAX * 4);    // [3][64][64] bf16
    unsigned int* pairs = (unsigned int*)(base + NBMAX * 4 + 24576);
    size_t sOff = ((size_t)NBMAX * 4 + 24576 + (size_t)nB * cap * 4 + 4096 + 255) & ~(size_t)255;
    int* starts = (int*)(base + sOff);                           // [N]
    int* degs   = starts + N;                                    // [N]
    size_t mOff = (sOff + (size_t)N * 8 + 255) & ~(size_t)255;
    unsigned short* meanh = (unsigned short*)(base + mOff);      // [N,64] bf16
    unsigned short* xh    = meanh + (size_t)N * 64;              // [N,64] bf16
    unsigned short* t2    = xh + (size_t)N * 64;                 // [N,32] bf16

    hipMemsetAsync(cursor, 0, NBMAX * 4, stream);

    const long total8 = (long)N * 64 / 8;
    const int pblocks = (E + PART_BLOCK * PART_EPT - 1) / (PART_BLOCK * PART_EPT);
    k_partition<<<pblocks, PART_BLOCK, 0, stream>>>(
        src, dst, cursor, pairs, E, cap,
        feat, xh, total8, ws1, wn1, ws2, wn2, wt);
    k_bucket_csr<<<nB, 256, (size_t)cap * 4, stream>>>(pairs, cursor, starts, degs, N, cap);

    const int gblocks = (N + 15) / 16;   // 16 nodes per block (4/wave)
    const int tblocks = (N + 127) / 128;

    k_gather_b64<<<gblocks, 256, 0, stream>>>(xh, pairs, starts, degs, meanh, N);
    k_gemm_mfma<<<tblocks, 256, 0, stream>>>(xh, meanh, wt, b1, b2, t2, out, N);
    k_gather_b32add<<<gblocks, 256, 0, stream>>>(t2, pairs, starts, degs, out, N);
}